// Round 9
// baseline (1679.852 us; speedup 1.0000x reference)
//
#include <hip/hip_runtime.h>
#include <cstdint>
#include <cstddef>

typedef __attribute__((ext_vector_type(8))) short short8;
typedef __attribute__((ext_vector_type(4))) float f32x4;
typedef __attribute__((ext_vector_type(4))) unsigned short us4;

#define N_SPK 64
#define M_UTT 10
#define T_SEQ 160
#define IN_F  40
#define H_DIM 256
#define B_TOT 640
#define G4    1024
#define FSTR  64   // flag stride in ints (256 B/flag: own cache line)

__device__ __forceinline__ unsigned short f2bf(float f) {
  unsigned int u = __float_as_uint(f);
  u += 0x7FFFu + ((u >> 16) & 1u);   // round-to-nearest-even
  return (unsigned short)(u >> 16);
}
__device__ __forceinline__ float b2f(unsigned short u) {
  return __uint_as_float(((unsigned int)u) << 16);
}
__device__ __forceinline__ float sigm(float x) {
  return 1.f / (1.f + __expf(-x));
}
__device__ __forceinline__ float tanh_fast(float x) {
  return 1.f - 2.f / (1.f + __expf(2.f * x));
}
__device__ __forceinline__ unsigned long long ato_ld(const unsigned long long* p) {
  return __hip_atomic_load(p, __ATOMIC_RELAXED, __HIP_MEMORY_SCOPE_AGENT);
}
__device__ __forceinline__ void ato_st(unsigned long long* p, unsigned long long v) {
  __hip_atomic_store(p, v, __ATOMIC_RELAXED, __HIP_MEMORY_SCOPE_AGENT);
}
__device__ __forceinline__ int flg_ld(const int* p) {
  return __hip_atomic_load(p, __ATOMIC_RELAXED, __HIP_MEMORY_SCOPE_AGENT);
}
__device__ __forceinline__ void flg_st(int* p, int v) {
  __hip_atomic_store(p, v, __ATOMIC_RELAXED, __HIP_MEMORY_SCOPE_AGENT);
}

// Raw barrier that does NOT drain vmcnt (keeps global loads in flight).
// lgkmcnt(0) orders the LDS writes; sched_barrier(0) after it prevents the
// compiler from hoisting dependent ops above the waitcnt (guide rule #18).
#define LDS_BARRIER() do {                                      \
  asm volatile("s_waitcnt lgkmcnt(0)" ::: "memory");            \
  __builtin_amdgcn_s_barrier();                                 \
  __builtin_amdgcn_sched_barrier(0);                            \
} while (0)

// ---------------------------------------------------------------------------
// Weight pack: B-fragment order for mfma_f32_16x16x32_bf16 (verified R1-R11).
// ---------------------------------------------------------------------------
__global__ void pack_w_kernel(const float* __restrict__ W, short* __restrict__ out,
                              int Kin, int Ktiles) {
  int idx = blockIdx.x * 256 + threadIdx.x;
  int total = 64 * Ktiles * 64;
  if (idx >= total) return;
  int lane = idx & 63;
  int rest = idx >> 6;
  int ks   = rest % Ktiles;
  int tile = rest / Ktiles;
  int n  = tile * 16 + (lane & 15);
  int k0 = ks * 32 + (lane >> 4) * 8;
  short8 v;
#pragma unroll
  for (int j = 0; j < 8; ++j) {
    int k = k0 + j;
    float f = (k < Kin) ? W[(size_t)n * Kin + k] : 0.f;
    v[j] = (short)f2bf(f);
  }
  *(short8*)&out[(size_t)idx * 8] = v;
}

__global__ void bias_sum_kernel(const float* __restrict__ a, const float* __restrict__ b,
                                float* __restrict__ o) {
  int i = blockIdx.x * 256 + threadIdx.x;
  if (i < G4) o[i] = a[i] + b[i];
}

// ---------------------------------------------------------------------------
// Layer-0 gate GEMM (fp32 seq, K pad 40->64). Verified R6-R11. 1600 blocks.
// ---------------------------------------------------------------------------
__global__ __launch_bounds__(256, 2)
void gate_gemm0(const float* __restrict__ seq, const short* __restrict__ Wp,
                const float* __restrict__ bias, unsigned short* __restrict__ G) {
  const int btile = blockIdx.x % 40;
  const int rest  = blockIdx.x / 40;
  const int tg    = rest & 3;
  const int chunk = rest >> 2;
  const int tid = threadIdx.x, lane = tid & 63, wave = tid >> 6;
  const int nl = lane & 15, mq = lane >> 4;

  for (int mg = 0; mg < 4; ++mg) {
    const int t0 = chunk * 16 + mg * 4;
    f32x4 acc[4][4];
#pragma unroll
    for (int q = 0; q < 4; ++q) {
      int tile = tg * 16 + wave + 4 * q;
      float bv = bias[tile * 16 + nl];
#pragma unroll
      for (int mm = 0; mm < 4; ++mm) acc[mm][q] = (f32x4){bv, bv, bv, bv};
    }
    for (int kt = 0; kt < 2; ++kt) {
      short8 a[4];
      const int m = btile * 16 + nl;
      const int k0 = kt * 32 + mq * 8;
#pragma unroll
      for (int mm = 0; mm < 4; ++mm) {
#pragma unroll
        for (int j = 0; j < 8; ++j) {
          int k = k0 + j;
          float f = (k < IN_F) ? seq[((size_t)m * T_SEQ + (t0 + mm)) * IN_F + k] : 0.f;
          a[mm][j] = (short)f2bf(f);
        }
      }
#pragma unroll
      for (int q = 0; q < 4; ++q) {
        int tile = tg * 16 + wave + 4 * q;
        short8 b = *(const short8*)&Wp[(((size_t)tile * 2 + kt) * 64 + lane) * 8];
#pragma unroll
        for (int mm = 0; mm < 4; ++mm)
          acc[mm][q] = __builtin_amdgcn_mfma_f32_16x16x32_bf16(a[mm], b, acc[mm][q], 0, 0, 0);
      }
    }
#pragma unroll
    for (int mm = 0; mm < 4; ++mm)
#pragma unroll
      for (int q = 0; q < 4; ++q) {
        int tile = tg * 16 + wave + 4 * q;
        us4 o;
#pragma unroll
        for (int r = 0; r < 4; ++r) o[r] = f2bf(acc[mm][q][r]);
        *(us4*)&G[(((size_t)(t0 + mm) * 40 + btile) * 64 + tile) * 256 + lane * 4] = o;
      }
  }
}

// ---------------------------------------------------------------------------
// Fused 3-layer pipeline. R21 = R17 protocol (proven 1404us) + template
// specialization on (L, HB): hb is compile-time, so R20's deferred-peer-pull
// schedule loses its dynamic-address VALU tax (R20 post-mortem: rotated
// ds_read offsets became runtime -> +500cy/step; that, not the overlap, was
// the regression). Deferred consumption is applied ONLY to L1/L2 (Wih's
// ~700cy of MFMA covers the in-flight peer pulls); L0 keeps R17's measured-
// best immediate-scatter schedule. Flags/ring/publish/swizzle: R17 verbatim.
// ---------------------------------------------------------------------------
template<int L, int HB>
__device__ __forceinline__ void rec_stage(
    int S,
    const short* __restrict__ Whhp, const short* __restrict__ Wihp,
    const unsigned short* __restrict__ G0, const float* __restrict__ biasl,
    unsigned long long* __restrict__ hxch, int* __restrict__ flags,
    const int* __restrict__ lens, float* __restrict__ c_state,
    unsigned short* h_sh, unsigned short* x_sh,
    float* bias_sh, short* wih_lds, int* len_sh)
{
  const int tid = threadIdx.x, lane = tid & 63, wave = tid >> 6;
  const int mq = lane >> 4, nl = lane & 15;
  const int lc = wave * 16 + nl;
  const int colown = HB * 64 + lc;
  unsigned long long* x64 = (unsigned long long*)x_sh;

  // Whh slice. L0: plain order (R17). L>=1: rotated so slot s holds physical
  // kt=(2*HB+s)&7 -- all compile-time now.
  short8 wregH[4][8];
#pragma unroll
  for (int g = 0; g < 4; ++g) {
    const int tile = g * 16 + HB * 4 + wave;
#pragma unroll
    for (int s = 0; s < 8; ++s) {
      const int ktp = (L == 0) ? s : ((2 * HB + s) & 7);
      wregH[g][s] = *(const short8*)&Whhp[(((size_t)tile * 8 + ktp) * 64 + lane) * 8];
    }
  }
  // Wih slice (L>=1): kt 0..3 in regs (16 frags), kt 4..7 in LDS (64 KB)
  short8 wregI[4][4];
  if (L >= 1) {
#pragma unroll
    for (int g = 0; g < 4; ++g) {
      const int tile = g * 16 + HB * 4 + wave;
#pragma unroll
      for (int kt = 0; kt < 4; ++kt)
        wregI[g][kt] = *(const short8*)&Wihp[(((size_t)tile * 8 + kt) * 64 + lane) * 8];
    }
    for (int i = tid; i < 4096; i += 256) {
      int tl = i >> 6, ln = i & 63;
      int lt = tl >> 2, kt4 = tl & 3;
      int gt = (lt >> 2) * 16 + HB * 4 + (lt & 3);
      *(short8*)&wih_lds[(lt * 4 + kt4) * 512 + ln * 8] =
          *(const short8*)&Wihp[(((size_t)gt * 8 + 4 + kt4) * 64 + ln) * 8];
    }
    for (int i = tid; i < 1024; i += 256) bias_sh[i] = biasl[i];
  }
  for (int i = tid; i < 64 * 264; i += 256) h_sh[i] = 0;
  if (tid < 64) len_sh[tid] = lens[S * 64 + tid];

  // c-state: thread-private registers (verified R14/R17).
  float creg[16];
#pragma unroll
  for (int i = 0; i < 16; ++i) creg[i] = 0.f;

  // L0: stage G0[0] into x_sh (thread-private 8B slots, conflict-free)
  if (L == 0) {
    us4 tmp[16];
#pragma unroll
    for (int m = 0; m < 4; ++m)
#pragma unroll
      for (int g = 0; g < 4; ++g) {
        const int tile = g * 16 + HB * 4 + wave;
        tmp[m * 4 + g] = *(const us4*)&G0[(((size_t)0 * 40 + S * 4 + m) * 64 + tile) * 256 + lane * 4];
      }
#pragma unroll
    for (int u = 0; u < 16; ++u)
      x64[u * 256 + tid] = *(unsigned long long*)&tmp[u];
  }
  __syncthreads();

  const int fself = L * 40 + S * 4 + HB;

  // ---- prologue (L>=1): confirm upstream published x[0], issue xr pulls ----
  unsigned long long xr[16];
  if (L >= 1) {
    if (tid < 4)
      while (flg_ld(&flags[((L - 1) * 40 + S * 4 + tid) * FSTR]) < 1) {}
    __syncthreads();
    const unsigned long long* xb0 =
        hxch + ((size_t)((0 * 3 + (L - 1)) * 10 + S)) * 4096;
#pragma unroll
    for (int u = 0; u < 16; ++u) xr[u] = ato_ld(&xb0[u * 256 + tid]);
  }
  unsigned long long pr[12];            // peer records (L>=1: loop-carried)

  for (int t = 0; t < T_SEQ; ++t) {
    const int par = t & 3;              // 4-deep parity

    // ---- back-pressure poll (wave 0) ----
    if (L < 2 && tid < 4)
      while (flg_ld(&flags[((L + 1) * 40 + S * 4 + tid) * FSTR]) < t - 3) {}

    f32x4 acc[4][4];
    if (L == 0) {
      // ================= L0: R17 schedule verbatim =================
#pragma unroll
      for (int m = 0; m < 4; ++m)
#pragma unroll
        for (int g = 0; g < 4; ++g) {
          unsigned long long v = x64[(m * 4 + g) * 256 + tid];
          us4 gv = *(us4*)&v;
#pragma unroll
          for (int r = 0; r < 4; ++r) acc[m][g][r] = b2f(gv[r]);
        }
#pragma unroll
      for (int kt = 0; kt < 8; ++kt) {
        short8 a[4];
#pragma unroll
        for (int m = 0; m < 4; ++m)
          a[m] = *(const short8*)&h_sh[(m * 16 + nl) * 264 + kt * 32 + mq * 8];
#pragma unroll
        for (int m = 0; m < 4; ++m)
#pragma unroll
          for (int g = 0; g < 4; ++g)
            acc[m][g] = __builtin_amdgcn_mfma_f32_16x16x32_bf16(a[m], wregH[g][kt], acc[m][g], 0, 0, 0);
      }
    } else {
      // ========== L1/L2: deferred-pr schedule (compile-time HB) ==========
#pragma unroll
      for (int g = 0; g < 4; ++g) {
        const int tile = g * 16 + HB * 4 + wave;
        float bv = bias_sh[tile * 16 + nl];
#pragma unroll
        for (int m = 0; m < 4; ++m) acc[m][g] = (f32x4){bv, bv, bv, bv};
      }
      // own-k Whh (s=0,1 -> physical kt 2*HB, 2*HB+1: own columns)
#pragma unroll
      for (int s = 0; s < 2; ++s) {
        const int ktp = (2 * HB + s) & 7;
        short8 a[4];
#pragma unroll
        for (int m = 0; m < 4; ++m)
          a[m] = *(const short8*)&h_sh[(m * 16 + nl) * 264 + ktp * 32 + mq * 8];
#pragma unroll
        for (int m = 0; m < 4; ++m)
#pragma unroll
          for (int g = 0; g < 4; ++g)
            acc[m][g] = __builtin_amdgcn_mfma_f32_16x16x32_bf16(a[m], wregH[g][s], acc[m][g], 0, 0, 0);
      }
      // x[t] scatter from prefetched regs; raw barrier keeps pr in flight
#pragma unroll
      for (int u = 0; u < 16; ++u) {
        int j = u * 256 + tid, pp = j >> 10, jj = j & 1023;
        *(unsigned long long*)&x_sh[(jj >> 4) * 264 + pp * 64 + (jj & 15) * 4] = xr[u];
      }
      LDS_BARRIER();                     // (B) x_sh ready; vmcnt NOT drained
      // Wih MFMA over x[t] -- covers the in-flight peer pulls
#pragma unroll
      for (int kt = 0; kt < 8; ++kt) {
        short8 a[4];
#pragma unroll
        for (int m = 0; m < 4; ++m)
          a[m] = *(const short8*)&x_sh[(m * 16 + nl) * 264 + kt * 32 + mq * 8];
#pragma unroll
        for (int g = 0; g < 4; ++g) {
          short8 b = (kt < 4) ? wregI[g][kt]
                              : *(const short8*)&wih_lds[((g * 4 + wave) * 4 + (kt - 4)) * 512 + lane * 8];
#pragma unroll
          for (int m = 0; m < 4; ++m)
            acc[m][g] = __builtin_amdgcn_mfma_f32_16x16x32_bf16(a[m], b, acc[m][g], 0, 0, 0);
        }
      }
      // consume peer pulls (issued at t-1 tail): scatter h[t-1] peer cols
      if (t > 0) {
#pragma unroll
        for (int u = 0; u < 12; ++u) {
          int j = u * 256 + tid;
          int pp = j >> 10, jj = j & 1023;
          int p = pp + (pp >= HB ? 1 : 0);
          *(unsigned long long*)&h_sh[(jj >> 4) * 264 + p * 64 + (jj & 15) * 4] = pr[u];
        }
      }
      __syncthreads();                   // (5') h[t-1] complete in LDS
      // peer-k Whh (s=2..7)
#pragma unroll
      for (int s = 2; s < 8; ++s) {
        const int ktp = (2 * HB + s) & 7;
        short8 a[4];
#pragma unroll
        for (int m = 0; m < 4; ++m)
          a[m] = *(const short8*)&h_sh[(m * 16 + nl) * 264 + ktp * 32 + mq * 8];
#pragma unroll
        for (int m = 0; m < 4; ++m)
#pragma unroll
          for (int g = 0; g < 4; ++g)
            acc[m][g] = __builtin_amdgcn_mfma_f32_16x16x32_bf16(a[m], wregH[g][s], acc[m][g], 0, 0, 0);
      }
    }
    // ---- gates (C/D: row=m*16+mq*4+r, col=nl), c in regs ----
    unsigned short hv[16];
#pragma unroll
    for (int m = 0; m < 4; ++m)
#pragma unroll
      for (int r = 0; r < 4; ++r) {
        const int row = m * 16 + mq * 4 + r;
        float c_old = creg[m * 4 + r];
        float cn = sigm(acc[m][1][r]) * c_old + sigm(acc[m][0][r]) * tanh_fast(acc[m][2][r]);
        float hn = sigm(acc[m][3][r]) * tanh_fast(cn);
        bool upd = t < len_sh[row];
        if (upd) creg[m * 4 + r] = cn;
        hv[m * 4 + r] = upd ? f2bf(hn) : h_sh[row * 264 + colown];
      }
    __syncthreads();                     // (1) all h_sh/x_sh reads done
#pragma unroll
    for (int m = 0; m < 4; ++m)
#pragma unroll
      for (int r = 0; r < 4; ++r)
        h_sh[(m * 16 + mq * 4 + r) * 264 + colown] = hv[m * 4 + r];
    __syncthreads();                     // (2) own cols in LDS
    // ---- publish own 8 KB slab (coalesced from LDS) ----
    unsigned long long* myslab =
        hxch + ((size_t)((par * 3 + L) * 10 + S) * 4 + HB) * 1024;
    for (int j = tid; j < 1024; j += 256) {
      int sample = j >> 4, l4 = j & 15;
      unsigned long long v =
          *(const unsigned long long*)&h_sh[sample * 264 + HB * 64 + l4 * 4];
      ato_st(&myslab[j], v);
    }
    __syncthreads();                     // (3) stores drained (vmcnt0)
    if (tid == 0) flg_st(&flags[fself * FSTR], t + 1);
    // ---- L0: prefetch G0[t+1] into x_sh in the poll shadow ----
    if (L == 0) {
      int tn = (t + 1 < T_SEQ) ? t + 1 : t;
      us4 tmp[16];
#pragma unroll
      for (int m = 0; m < 4; ++m)
#pragma unroll
        for (int g = 0; g < 4; ++g) {
          const int tile = g * 16 + HB * 4 + wave;
          tmp[m * 4 + g] = *(const us4*)&G0[(((size_t)tn * 40 + S * 4 + m) * 64 + tile) * 256 + lane * 4];
        }
#pragma unroll
      for (int u = 0; u < 16; ++u)
        x64[u * 256 + tid] = *(unsigned long long*)&tmp[u];
    }
    if (t + 1 < T_SEQ) {
      // ---- polls in PARALLEL waves: peers (wave 0), upstream t+2 (wave 1) --
      if (tid < 3) {
        int p = tid + (tid >= HB ? 1 : 0);
        while (flg_ld(&flags[(L * 40 + S * 4 + p) * FSTR]) < t + 1) {}
      }
      if (L >= 1 && tid >= 64 && tid < 68)
        while (flg_ld(&flags[((L - 1) * 40 + S * 4 + (tid - 64)) * FSTR]) < t + 2) {}
      __syncthreads();                   // (4)
      if (L >= 1) {
        // issue x[t+1] pulls then peer pulls; consumed next step (deferred)
        const unsigned long long* xb =
            hxch + ((size_t)((((t + 1) & 3) * 3 + (L - 1)) * 10 + S)) * 4096;
#pragma unroll
        for (int u = 0; u < 16; ++u) xr[u] = ato_ld(&xb[u * 256 + tid]);
#pragma unroll
        for (int u = 0; u < 12; ++u) {
          int j = u * 256 + tid;
          int pp = j >> 10, jj = j & 1023;
          int p = pp + (pp >= HB ? 1 : 0);
          pr[u] = ato_ld(&hxch[((size_t)((par * 3 + L) * 10 + S) * 4 + p) * 1024 + jj]);
        }
      } else {
        // L0: R17 immediate pull + scatter + barrier (5)
        unsigned long long prl[12];
#pragma unroll
        for (int u = 0; u < 12; ++u) {
          int j = u * 256 + tid;
          int pp = j >> 10, jj = j & 1023;
          int p = pp + (pp >= HB ? 1 : 0);
          prl[u] = ato_ld(&hxch[((size_t)((par * 3 + L) * 10 + S) * 4 + p) * 1024 + jj]);
        }
#pragma unroll
        for (int u = 0; u < 12; ++u) {
          int j = u * 256 + tid;
          int pp = j >> 10, jj = j & 1023;
          int p = pp + (pp >= HB ? 1 : 0);
          *(unsigned long long*)&h_sh[(jj >> 4) * 264 + p * 64 + (jj & 15) * 4] = prl[u];
        }
        __syncthreads();                 // (5) h[t] complete in LDS
      }
    }
  }
  if (L == 2) {
#pragma unroll
    for (int m = 0; m < 4; ++m)
#pragma unroll
      for (int r = 0; r < 4; ++r) {
        const int row = m * 16 + mq * 4 + r;
        c_state[((size_t)S * 64 + row) * 256 + colown] = creg[m * 4 + r];
      }
  }
}

__global__ __launch_bounds__(256, 1)
void fused_lstm(const short* __restrict__ Whhp_all, const short* __restrict__ Wih1p,
                const short* __restrict__ Wih2p, const float* __restrict__ biasc,
                const unsigned short* __restrict__ G0, const int* __restrict__ lens,
                unsigned long long* __restrict__ hxch, int* __restrict__ flags,
                float* __restrict__ c_state)
{
  __shared__ unsigned short h_sh[64 * 264];   // 33792 B
  __shared__ unsigned short x_sh[64 * 264];   // 33792 B (L0: G0 staging)
  __shared__ float bias_sh[1024];             // 4096 B
  __shared__ short wih_lds[16 * 4 * 512];     // 65536 B   (total ~137 KB <= 160)
  __shared__ int len_sh[64];

  // XCD-aware role decode (launch = 128 blocks; R13's PROVEN mapping):
  // the 4 hb partners of a group share bid%8 == same XCD (FETCH -38%).
  const int bid  = blockIdx.x;                // 0..127
  const int xcd  = bid & 7;
  const int j    = bid >> 3;                  // 0..15 slot on this XCD
  const int g    = (j >> 2) * 8 + xcd;        // logical group 0..31
  if (g >= 30) return;
  const int L  = g / 10;
  const int S  = g % 10;
  const int hb = j & 3;

#define DISPATCH(LL, OFF, WIH, BIAS)                                          \
  do {                                                                        \
    if (hb == 0)      rec_stage<LL, 0>(S, Whhp_all + OFF, WIH, G0, BIAS,      \
        hxch, flags, lens, c_state, h_sh, x_sh, bias_sh, wih_lds, len_sh);    \
    else if (hb == 1) rec_stage<LL, 1>(S, Whhp_all + OFF, WIH, G0, BIAS,      \
        hxch, flags, lens, c_state, h_sh, x_sh, bias_sh, wih_lds, len_sh);    \
    else if (hb == 2) rec_stage<LL, 2>(S, Whhp_all + OFF, WIH, G0, BIAS,      \
        hxch, flags, lens, c_state, h_sh, x_sh, bias_sh, wih_lds, len_sh);    \
    else              rec_stage<LL, 3>(S, Whhp_all + OFF, WIH, G0, BIAS,      \
        hxch, flags, lens, c_state, h_sh, x_sh, bias_sh, wih_lds, len_sh);    \
  } while (0)

  if (L == 0)      DISPATCH(0, 0,      (const short*)nullptr, (const float*)nullptr);
  else if (L == 1) DISPATCH(1, 262144, Wih1p, biasc + G4);
  else             DISPATCH(2, 524288, Wih2p, biasc + 2 * G4);
#undef DISPATCH
}

// ---------------------------------------------------------------------------
// Epilogue (verified R1-R11). E aliases c_state.
// ---------------------------------------------------------------------------
__global__ void k_norm(const float* __restrict__ E, float* __restrict__ E1,
                       float* __restrict__ En) {
  int row  = blockIdx.x * 4 + (threadIdx.x >> 6);
  int lane = threadIdx.x & 63;
  const float* e = E + (size_t)row * H_DIM;
  float v[4]; float ss = 0.f;
#pragma unroll
  for (int j = 0; j < 4; ++j) { v[j] = e[lane + 64 * j]; ss += v[j] * v[j]; }
#pragma unroll
  for (int m = 32; m >= 1; m >>= 1) ss += __shfl_xor(ss, m, 64);
  float nrm  = sqrtf(ss);
  float inv1 = 1.f / fmaxf(nrm, 1e-12f);
  float inv2 = 1.f / fmaxf(nrm * inv1, 1e-8f);
#pragma unroll
  for (int j = 0; j < 4; ++j) {
    float e1 = v[j] * inv1;
    E1[(size_t)row * H_DIM + lane + 64 * j] = e1;
    En[(size_t)row * H_DIM + lane + 64 * j] = e1 * inv2;
  }
}

__global__ void k_cent(const float* __restrict__ E1, float* __restrict__ C,
                       float* __restrict__ CnT) {
  int n = blockIdx.x;
  int lane = threadIdx.x;  // 64
  float v[4]; float ss = 0.f;
#pragma unroll
  for (int j = 0; j < 4; ++j) {
    int col = lane + 64 * j;
    float s = 0.f;
    for (int m = 0; m < M_UTT; ++m) s += E1[((size_t)n * M_UTT + m) * H_DIM + col];
    v[j] = s / (float)M_UTT;
    ss += v[j] * v[j];
  }
#pragma unroll
  for (int m = 32; m >= 1; m >>= 1) ss += __shfl_xor(ss, m, 64);
  float inv = 1.f / fmaxf(sqrtf(ss), 1e-8f);
#pragma unroll
  for (int j = 0; j < 4; ++j) {
    int col = lane + 64 * j;
    C[(size_t)n * H_DIM + col]  = v[j];
    CnT[(size_t)col * N_SPK + n] = v[j] * inv;
  }
}

__global__ void k_cm(const float* __restrict__ E1, const float* __restrict__ C,
                     float* __restrict__ Cmn) {
  int b    = blockIdx.x * 4 + (threadIdx.x >> 6);
  int lane = threadIdx.x & 63;
  int spk  = b / M_UTT;
  float v[4]; float ss = 0.f;
#pragma unroll
  for (int j = 0; j < 4; ++j) {
    int col = lane + 64 * j;
    v[j] = ((float)M_UTT * C[(size_t)spk * H_DIM + col] + E1[(size_t)b * H_DIM + col])
           / (float)(M_UTT - 1);
    ss += v[j] * v[j];
  }
#pragma unroll
  for (int m = 32; m >= 1; m >>= 1) ss += __shfl_xor(ss, m, 64);
  float inv = 1.f / fmaxf(sqrtf(ss), 1e-8f);
#pragma unroll
  for (int j = 0; j < 4; ++j)
    Cmn[(size_t)b * H_DIM + lane + 64 * j] = v[j] * inv;
}

__global__ void k_sim(const float* __restrict__ En, const float* __restrict__ CnT,
                      const float* __restrict__ Cmn, const float* __restrict__ w_sim,
                      const float* __restrict__ b_sim, float* __restrict__ S) {
  int b = blockIdx.x;
  int n = threadIdx.x;  // 64
  int diag = b / M_UTT;
  float w = w_sim[0], bb = b_sim[0];
  float s = 0.f;
  for (int k = 0; k < H_DIM; ++k) {
    float en = En[(size_t)b * H_DIM + k];
    float c  = (n == diag) ? Cmn[(size_t)b * H_DIM + k] : CnT[(size_t)k * N_SPK + n];
    s += en * c;
  }
  S[(size_t)b * N_SPK + n] = s * w + bb;
}

// ---------------------------------------------------------------------------
// Workspace layout (bytes). Total ~219 MB (proven available). R13 map.
// ---------------------------------------------------------------------------
#define O_WHH   0ull            // 3 x 524288 = 1572864
#define O_WIH0  1572864ull      // 131072
#define O_WIH1  1703936ull      // 524288
#define O_WIH2  2228224ull      // 524288
#define O_BIAS  2752512ull      // 12288
#define O_CST   2764800ull      // 655360 (fp32 c of layer2 = E)
#define O_E1    3420160ull      // 655360
#define O_EN    4075520ull      // 655360
#define O_C     4730880ull      // 65536
#define O_CNT   4796416ull      // 65536
#define O_CMN   4861952ull      // 655360
#define O_FLG   5517312ull      // 30720 (120 flags x 256 B)
#define O_HXCH  5548032ull      // 3932160 (4par x 3l x 10S x 4hb x 8KB)
#define O_G0    9480192ull      // 209715200 -> end 219195392

extern "C" void kernel_launch(void* const* d_in, const int* in_sizes, int n_in,
                              void* d_out, int out_size, void* d_ws, size_t ws_size,
                              hipStream_t stream) {
  const float* seq   = (const float*)d_in[0];
  const int*   lens  = (const int*)d_in[1];
  const float* w_sim = (const float*)d_in[2];
  const float* b_sim = (const float*)d_in[3];
  const float* Wih[3] = {(const float*)d_in[4],  (const float*)d_in[8],  (const float*)d_in[12]};
  const float* Whh[3] = {(const float*)d_in[5],  (const float*)d_in[9],  (const float*)d_in[13]};
  const float* bih[3] = {(const float*)d_in[6],  (const float*)d_in[10], (const float*)d_in[14]};
  const float* bhh[3] = {(const float*)d_in[7],  (const float*)d_in[11], (const float*)d_in[15]};

  char* ws = (char*)d_ws;
  short* Whhp_all = (short*)(ws + O_WHH);
  short* Wihp[3] = {(short*)(ws + O_WIH0), (short*)(ws + O_WIH1), (short*)(ws + O_WIH2)};
  float* biasc = (float*)(ws + O_BIAS);
  float* c_state = (float*)(ws + O_CST);
  float* E1  = (float*)(ws + O_E1);
  float* En  = (float*)(ws + O_EN);
  float* C   = (float*)(ws + O_C);
  float* CnT = (float*)(ws + O_CNT);
  float* Cmn = (float*)(ws + O_CMN);
  int* flags = (int*)(ws + O_FLG);
  unsigned long long* hxch = (unsigned long long*)(ws + O_HXCH);
  unsigned short* G0 = (unsigned short*)(ws + O_G0);
  float* S = (float*)d_out;

  // ---- packs ----
  pack_w_kernel<<<32, 256, 0, stream>>>(Wih[0], Wihp[0], IN_F, 2);
  pack_w_kernel<<<128, 256, 0, stream>>>(Whh[0], Whhp_all, H_DIM, 8);
  pack_w_kernel<<<128, 256, 0, stream>>>(Whh[1], Whhp_all + 262144, H_DIM, 8);
  pack_w_kernel<<<128, 256, 0, stream>>>(Whh[2], Whhp_all + 524288, H_DIM, 8);
  pack_w_kernel<<<128, 256, 0, stream>>>(Wih[1], Wihp[1], H_DIM, 8);
  pack_w_kernel<<<128, 256, 0, stream>>>(Wih[2], Wihp[2], H_DIM, 8);
  for (int l = 0; l < 3; ++l)
    bias_sum_kernel<<<4, 256, 0, stream>>>(bih[l], bhh[l], biasc + l * G4);

  // ---- layer-0 gate GEMM (full T, bias folded) ----
  gate_gemm0<<<1600, 256, 0, stream>>>(seq, Wihp[0], biasc, G0);

  // ---- fused 3-layer pipeline (R17 protocol; L1/L2 deferred-pr, tmpl HB) --
  (void)hipMemsetAsync(ws + O_FLG, 0, 30720, stream);
  fused_lstm<<<128, 256, 0, stream>>>(Whhp_all, Wihp[1], Wihp[2], biasc, G0, lens,
                                      hxch, flags, c_state);

  // ---- similarity epilogue (E = c_state) ----
  k_norm<<<160, 256, 0, stream>>>(c_state, E1, En);
  k_cent<<<N_SPK, 64, 0, stream>>>(E1, C, CnT);
  k_cm<<<160, 256, 0, stream>>>(E1, C, Cmn);
  k_sim<<<B_TOT, 64, 0, stream>>>(En, CnT, Cmn, w_sim, b_sim, S);
}

// Round 10
// 1536.764 us; speedup vs baseline: 1.0931x; 1.0931x over previous
//
#include <hip/hip_runtime.h>
#include <cstdint>
#include <cstddef>

typedef __attribute__((ext_vector_type(8))) short short8;
typedef __attribute__((ext_vector_type(4))) float f32x4;
typedef __attribute__((ext_vector_type(4))) unsigned short us4;

#define N_SPK 64
#define M_UTT 10
#define T_SEQ 160
#define IN_F  40
#define H_DIM 256
#define B_TOT 640
#define G4    1024
#define FSTR  64   // flag stride in ints (256 B/flag: own cache line)

__device__ __forceinline__ unsigned short f2bf(float f) {
  unsigned int u = __float_as_uint(f);
  u += 0x7FFFu + ((u >> 16) & 1u);   // round-to-nearest-even
  return (unsigned short)(u >> 16);
}
__device__ __forceinline__ float b2f(unsigned short u) {
  return __uint_as_float(((unsigned int)u) << 16);
}
__device__ __forceinline__ float sigm(float x) {
  return 1.f / (1.f + __expf(-x));
}
__device__ __forceinline__ float tanh_fast(float x) {
  return 1.f - 2.f / (1.f + __expf(2.f * x));
}
__device__ __forceinline__ unsigned long long ato_ld(const unsigned long long* p) {
  return __hip_atomic_load(p, __ATOMIC_RELAXED, __HIP_MEMORY_SCOPE_AGENT);
}
__device__ __forceinline__ void ato_st(unsigned long long* p, unsigned long long v) {
  __hip_atomic_store(p, v, __ATOMIC_RELAXED, __HIP_MEMORY_SCOPE_AGENT);
}
__device__ __forceinline__ int flg_ld(const int* p) {
  return __hip_atomic_load(p, __ATOMIC_RELAXED, __HIP_MEMORY_SCOPE_AGENT);
}
__device__ __forceinline__ void flg_st(int* p, int v) {
  __hip_atomic_store(p, v, __ATOMIC_RELAXED, __HIP_MEMORY_SCOPE_AGENT);
}

// ---------------------------------------------------------------------------
// Merged weight pack: all 6 tensors in ONE launch (segment decode by block).
// Inner body identical to the verified pack_w_kernel (R1-R11); segment sizes
// are exact multiples of 256 so no bounds checks change behavior.
//   blocks 0..31    : Wih0 (Kin=40,  Ktiles=2) -> ws_wih0
//   blocks 32..159  : Whh0 (Kin=256, Ktiles=8) -> ws_whh + 0
//   blocks 160..287 : Whh1                      -> ws_whh + 262144
//   blocks 288..415 : Whh2                      -> ws_whh + 524288
//   blocks 416..543 : Wih1                      -> ws_wih1
//   blocks 544..671 : Wih2                      -> ws_wih2
// ---------------------------------------------------------------------------
__global__ void pack_all_kernel(
    const float* __restrict__ Wih0, const float* __restrict__ Whh0,
    const float* __restrict__ Whh1, const float* __restrict__ Whh2,
    const float* __restrict__ Wih1, const float* __restrict__ Wih2,
    short* __restrict__ ws_wih0, short* __restrict__ ws_whh,
    short* __restrict__ ws_wih1, short* __restrict__ ws_wih2) {
  const int b = blockIdx.x;
  const float* W; short* out; int Kin, Ktiles, b0;
  if (b < 32)       { W = Wih0; out = ws_wih0;          Kin = IN_F;  Ktiles = 2; b0 = 0;   }
  else if (b < 160) { W = Whh0; out = ws_whh;           Kin = H_DIM; Ktiles = 8; b0 = 32;  }
  else if (b < 288) { W = Whh1; out = ws_whh + 262144;  Kin = H_DIM; Ktiles = 8; b0 = 160; }
  else if (b < 416) { W = Whh2; out = ws_whh + 524288;  Kin = H_DIM; Ktiles = 8; b0 = 288; }
  else if (b < 544) { W = Wih1; out = ws_wih1;          Kin = H_DIM; Ktiles = 8; b0 = 416; }
  else              { W = Wih2; out = ws_wih2;          Kin = H_DIM; Ktiles = 8; b0 = 544; }
  int idx = (b - b0) * 256 + threadIdx.x;
  int total = 64 * Ktiles * 64;
  if (idx >= total) return;
  int lane = idx & 63;
  int rest = idx >> 6;
  int ks   = rest % Ktiles;
  int tile = rest / Ktiles;
  int n  = tile * 16 + (lane & 15);
  int k0 = ks * 32 + (lane >> 4) * 8;
  short8 v;
#pragma unroll
  for (int j = 0; j < 8; ++j) {
    int k = k0 + j;
    float f = (k < Kin) ? W[(size_t)n * Kin + k] : 0.f;
    v[j] = (short)f2bf(f);
  }
  *(short8*)&out[(size_t)idx * 8] = v;
}

// Merged bias sums: 3 layers in one 12-block launch (exact 3x1024 coverage).
__global__ void bias_all_kernel(
    const float* __restrict__ b0a, const float* __restrict__ b0b,
    const float* __restrict__ b1a, const float* __restrict__ b1b,
    const float* __restrict__ b2a, const float* __restrict__ b2b,
    float* __restrict__ o) {
  int i = blockIdx.x * 256 + threadIdx.x;   // 0..3071
  int l = i >> 10, j = i & 1023;
  const float* a = (l == 0) ? b0a : (l == 1) ? b1a : b2a;
  const float* b = (l == 0) ? b0b : (l == 1) ? b1b : b2b;
  o[l * 1024 + j] = a[j] + b[j];
}

// ---------------------------------------------------------------------------
// Layer-0 gate GEMM (fp32 seq, K pad 40->64). Verified R6-R11. 1600 blocks.
// ---------------------------------------------------------------------------
__global__ __launch_bounds__(256, 2)
void gate_gemm0(const float* __restrict__ seq, const short* __restrict__ Wp,
                const float* __restrict__ bias, unsigned short* __restrict__ G) {
  const int btile = blockIdx.x % 40;
  const int rest  = blockIdx.x / 40;
  const int tg    = rest & 3;
  const int chunk = rest >> 2;
  const int tid = threadIdx.x, lane = tid & 63, wave = tid >> 6;
  const int nl = lane & 15, mq = lane >> 4;

  for (int mg = 0; mg < 4; ++mg) {
    const int t0 = chunk * 16 + mg * 4;
    f32x4 acc[4][4];
#pragma unroll
    for (int q = 0; q < 4; ++q) {
      int tile = tg * 16 + wave + 4 * q;
      float bv = bias[tile * 16 + nl];
#pragma unroll
      for (int mm = 0; mm < 4; ++mm) acc[mm][q] = (f32x4){bv, bv, bv, bv};
    }
    for (int kt = 0; kt < 2; ++kt) {
      short8 a[4];
      const int m = btile * 16 + nl;
      const int k0 = kt * 32 + mq * 8;
#pragma unroll
      for (int mm = 0; mm < 4; ++mm) {
#pragma unroll
        for (int j = 0; j < 8; ++j) {
          int k = k0 + j;
          float f = (k < IN_F) ? seq[((size_t)m * T_SEQ + (t0 + mm)) * IN_F + k] : 0.f;
          a[mm][j] = (short)f2bf(f);
        }
      }
#pragma unroll
      for (int q = 0; q < 4; ++q) {
        int tile = tg * 16 + wave + 4 * q;
        short8 b = *(const short8*)&Wp[(((size_t)tile * 2 + kt) * 64 + lane) * 8];
#pragma unroll
        for (int mm = 0; mm < 4; ++mm)
          acc[mm][q] = __builtin_amdgcn_mfma_f32_16x16x32_bf16(a[mm], b, acc[mm][q], 0, 0, 0);
      }
    }
#pragma unroll
    for (int mm = 0; mm < 4; ++mm)
#pragma unroll
      for (int q = 0; q < 4; ++q) {
        int tile = tg * 16 + wave + 4 * q;
        us4 o;
#pragma unroll
        for (int r = 0; r < 4; ++r) o[r] = f2bf(acc[mm][q][r]);
        *(us4*)&G[(((size_t)(t0 + mm) * 40 + btile) * 64 + tile) * 256 + lane * 4] = o;
      }
  }
}

// ---------------------------------------------------------------------------
// Fused 3-layer pipeline: R17 VERBATIM (measured best, 1404us). R18-R21
// structural probes (8-wave m-split, deferred peer pulls with and without
// compile-time hb) all regressed; this schedule + protocol is the converged
// local optimum. Key proven pieces: coalesced publish + drain-barrier before
// flag; x[t+1] register prefetch issued at tail with parallel-wave polls;
// c-state in registers; XCD-aware role decode (4 hb partners share an XCD).
// ---------------------------------------------------------------------------
template<int L>
__device__ __forceinline__ void rec_stage(
    int S, int hb,
    const short* __restrict__ Whhp, const short* __restrict__ Wihp,
    const unsigned short* __restrict__ G0, const float* __restrict__ biasl,
    unsigned long long* __restrict__ hxch, int* __restrict__ flags,
    const int* __restrict__ lens, float* __restrict__ c_state,
    unsigned short* h_sh, unsigned short* x_sh,
    float* bias_sh, short* wih_lds, int* len_sh)
{
  const int tid = threadIdx.x, lane = tid & 63, wave = tid >> 6;
  const int mq = lane >> 4, nl = lane & 15;
  const int lc = wave * 16 + nl;
  const int colown = hb * 64 + lc;
  unsigned long long* x64 = (unsigned long long*)x_sh;

  // Whh slice: 4 tiles x 8 kt = 32 frags (AGPR-parked, R6-R11 proven)
  short8 wregH[4][8];
#pragma unroll
  for (int g = 0; g < 4; ++g) {
    const int tile = g * 16 + hb * 4 + wave;
#pragma unroll
    for (int kt = 0; kt < 8; ++kt)
      wregH[g][kt] = *(const short8*)&Whhp[(((size_t)tile * 8 + kt) * 64 + lane) * 8];
  }
  // Wih slice (L>=1): kt 0..3 in regs (16 frags), kt 4..7 in LDS (64 KB)
  short8 wregI[4][4];
  if (L >= 1) {
#pragma unroll
    for (int g = 0; g < 4; ++g) {
      const int tile = g * 16 + hb * 4 + wave;
#pragma unroll
      for (int kt = 0; kt < 4; ++kt)
        wregI[g][kt] = *(const short8*)&Wihp[(((size_t)tile * 8 + kt) * 64 + lane) * 8];
    }
    for (int i = tid; i < 4096; i += 256) {
      int tl = i >> 6, ln = i & 63;
      int lt = tl >> 2, kt4 = tl & 3;
      int gt = (lt >> 2) * 16 + hb * 4 + (lt & 3);
      *(short8*)&wih_lds[(lt * 4 + kt4) * 512 + ln * 8] =
          *(const short8*)&Wihp[(((size_t)gt * 8 + 4 + kt4) * 64 + ln) * 8];
    }
    for (int i = tid; i < 1024; i += 256) bias_sh[i] = biasl[i];
  }
  for (int i = tid; i < 64 * 264; i += 256) h_sh[i] = 0;
  if (tid < 64) len_sh[tid] = lens[S * 64 + tid];

  // c-state: thread-private registers (same thread updates same (row,col)
  // every step; verified numerically in R14).
  float creg[16];
#pragma unroll
  for (int i = 0; i < 16; ++i) creg[i] = 0.f;

  // L0: stage G0[0] into x_sh (thread-private 8B slots, conflict-free)
  if (L == 0) {
    us4 tmp[16];
#pragma unroll
    for (int m = 0; m < 4; ++m)
#pragma unroll
      for (int g = 0; g < 4; ++g) {
        const int tile = g * 16 + hb * 4 + wave;
        tmp[m * 4 + g] = *(const us4*)&G0[(((size_t)0 * 40 + S * 4 + m) * 64 + tile) * 256 + lane * 4];
      }
#pragma unroll
    for (int u = 0; u < 16; ++u)
      x64[u * 256 + tid] = *(unsigned long long*)&tmp[u];
  }
  __syncthreads();

  const int fself = L * 40 + S * 4 + hb;

  // ---- prologue (L>=1): confirm upstream published x[0], pull into regs ----
  unsigned long long xr[16];
  if (L >= 1) {
    if (tid < 4)
      while (flg_ld(&flags[((L - 1) * 40 + S * 4 + tid) * FSTR]) < 1) {}
    __syncthreads();
    const unsigned long long* xb0 =
        hxch + ((size_t)((0 * 3 + (L - 1)) * 10 + S)) * 4096;
#pragma unroll
    for (int u = 0; u < 16; ++u) xr[u] = ato_ld(&xb0[u * 256 + tid]);
  }

  for (int t = 0; t < T_SEQ; ++t) {
    const int par = t & 3;              // 4-deep parity

    // ---- back-pressure poll (wave 0; ordering enforced by barriers B/(1)) --
    if (L < 2 && tid < 4)
      while (flg_ld(&flags[((L + 1) * 40 + S * 4 + tid) * FSTR]) < t - 3) {}

    // ---- x[t] scatter from prefetched regs (L>=1) ----
    if (L >= 1) {
#pragma unroll
      for (int u = 0; u < 16; ++u) {
        int j = u * 256 + tid, pp = j >> 10, jj = j & 1023;
        *(unsigned long long*)&x_sh[(jj >> 4) * 264 + pp * 64 + (jj & 15) * 4] = xr[u];
      }
      __syncthreads();                   // (B) x_sh ready; h_sh reads fenced
    }
    // ---- acc init: L==0 from staged G0 (LDS), else bias ----
    f32x4 acc[4][4];
    if (L == 0) {
#pragma unroll
      for (int m = 0; m < 4; ++m)
#pragma unroll
        for (int g = 0; g < 4; ++g) {
          unsigned long long v = x64[(m * 4 + g) * 256 + tid];
          us4 gv = *(us4*)&v;
#pragma unroll
          for (int r = 0; r < 4; ++r) acc[m][g][r] = b2f(gv[r]);
        }
    } else {
#pragma unroll
      for (int g = 0; g < 4; ++g) {
        const int tile = g * 16 + hb * 4 + wave;
        float bv = bias_sh[tile * 16 + nl];
#pragma unroll
        for (int m = 0; m < 4; ++m) acc[m][g] = (f32x4){bv, bv, bv, bv};
      }
    }
    // ---- Whh MFMA over h[t-1] ----
#pragma unroll
    for (int kt = 0; kt < 8; ++kt) {
      short8 a[4];
#pragma unroll
      for (int m = 0; m < 4; ++m)
        a[m] = *(const short8*)&h_sh[(m * 16 + nl) * 264 + kt * 32 + mq * 8];
#pragma unroll
      for (int m = 0; m < 4; ++m)
#pragma unroll
        for (int g = 0; g < 4; ++g)
          acc[m][g] = __builtin_amdgcn_mfma_f32_16x16x32_bf16(a[m], wregH[g][kt], acc[m][g], 0, 0, 0);
    }
    // ---- Wih MFMA over x[t] (L>=1) ----
    if (L >= 1) {
#pragma unroll
      for (int kt = 0; kt < 8; ++kt) {
        short8 a[4];
#pragma unroll
        for (int m = 0; m < 4; ++m)
          a[m] = *(const short8*)&x_sh[(m * 16 + nl) * 264 + kt * 32 + mq * 8];
#pragma unroll
        for (int g = 0; g < 4; ++g) {
          short8 b = (kt < 4) ? wregI[g][kt]
                              : *(const short8*)&wih_lds[((g * 4 + wave) * 4 + (kt - 4)) * 512 + lane * 8];
#pragma unroll
          for (int m = 0; m < 4; ++m)
            acc[m][g] = __builtin_amdgcn_mfma_f32_16x16x32_bf16(a[m], b, acc[m][g], 0, 0, 0);
        }
      }
    }
    // ---- gates (C/D: row=m*16+mq*4+r, col=nl), c in regs ----
    unsigned short hv[16];
#pragma unroll
    for (int m = 0; m < 4; ++m)
#pragma unroll
      for (int r = 0; r < 4; ++r) {
        const int row = m * 16 + mq * 4 + r;
        float c_old = creg[m * 4 + r];
        float cn = sigm(acc[m][1][r]) * c_old + sigm(acc[m][0][r]) * tanh_fast(acc[m][2][r]);
        float hn = sigm(acc[m][3][r]) * tanh_fast(cn);
        bool upd = t < len_sh[row];
        if (upd) creg[m * 4 + r] = cn;
        hv[m * 4 + r] = upd ? f2bf(hn) : h_sh[row * 264 + colown];
      }
    __syncthreads();                     // (1) all h_sh/x_sh reads done
#pragma unroll
    for (int m = 0; m < 4; ++m)
#pragma unroll
      for (int r = 0; r < 4; ++r)
        h_sh[(m * 16 + mq * 4 + r) * 264 + colown] = hv[m * 4 + r];
    __syncthreads();                     // (2) own cols in LDS
    // ---- publish own 8 KB slab (R13 form: coalesced from LDS) ----
    unsigned long long* myslab =
        hxch + ((size_t)((par * 3 + L) * 10 + S) * 4 + hb) * 1024;
    for (int j = tid; j < 1024; j += 256) {
      int sample = j >> 4, l4 = j & 15;
      unsigned long long v =
          *(const unsigned long long*)&h_sh[sample * 264 + hb * 64 + l4 * 4];
      ato_st(&myslab[j], v);
    }
    __syncthreads();                     // (3) stores drained (vmcnt0)
    if (tid == 0) flg_st(&flags[fself * FSTR], t + 1);
    // ---- L0: prefetch G0[t+1] into x_sh in the poll/pull shadow ----
    if (L == 0) {
      int tn = (t + 1 < T_SEQ) ? t + 1 : t;
      us4 tmp[16];
#pragma unroll
      for (int m = 0; m < 4; ++m)
#pragma unroll
        for (int g = 0; g < 4; ++g) {
          const int tile = g * 16 + hb * 4 + wave;
          tmp[m * 4 + g] = *(const us4*)&G0[(((size_t)tn * 40 + S * 4 + m) * 64 + tile) * 256 + lane * 4];
        }
#pragma unroll
      for (int u = 0; u < 16; ++u)
        x64[u * 256 + tid] = *(unsigned long long*)&tmp[u];
    }
    if (t + 1 < T_SEQ) {
      // ---- polls in PARALLEL waves: peers (wave 0), upstream t+2 (wave 1) --
      if (tid < 3) {
        int p = tid + (tid >= hb ? 1 : 0);
        while (flg_ld(&flags[(L * 40 + S * 4 + p) * FSTR]) < t + 1) {}
      }
      if (L >= 1 && tid >= 64 && tid < 68)
        while (flg_ld(&flags[((L - 1) * 40 + S * 4 + (tid - 64)) * FSTR]) < t + 2) {}
      __syncthreads();                   // (4)
      // ---- issue x[t+1] pulls (regs, L>=1) + 3 peer slab pulls ----
      if (L >= 1) {
        const unsigned long long* xb =
            hxch + ((size_t)((((t + 1) & 3) * 3 + (L - 1)) * 10 + S)) * 4096;
#pragma unroll
        for (int u = 0; u < 16; ++u) xr[u] = ato_ld(&xb[u * 256 + tid]);
      }
      {
        unsigned long long pr[12];
#pragma unroll
        for (int u = 0; u < 12; ++u) {
          int j = u * 256 + tid;
          int pp = j >> 10, jj = j & 1023;
          int p = pp + (pp >= hb ? 1 : 0);
          pr[u] = ato_ld(&hxch[((size_t)((par * 3 + L) * 10 + S) * 4 + p) * 1024 + jj]);
        }
#pragma unroll
        for (int u = 0; u < 12; ++u) {
          int j = u * 256 + tid;
          int pp = j >> 10, jj = j & 1023;
          int p = pp + (pp >= hb ? 1 : 0);
          *(unsigned long long*)&h_sh[(jj >> 4) * 264 + p * 64 + (jj & 15) * 4] = pr[u];
        }
      }
      __syncthreads();                   // (5) h[t] complete in LDS
    }
  }
  if (L == 2) {
#pragma unroll
    for (int m = 0; m < 4; ++m)
#pragma unroll
      for (int r = 0; r < 4; ++r) {
        const int row = m * 16 + mq * 4 + r;
        c_state[((size_t)S * 64 + row) * 256 + colown] = creg[m * 4 + r];
      }
  }
}

__global__ __launch_bounds__(256, 1)
void fused_lstm(const short* __restrict__ Whhp_all, const short* __restrict__ Wih1p,
                const short* __restrict__ Wih2p, const float* __restrict__ biasc,
                const unsigned short* __restrict__ G0, const int* __restrict__ lens,
                unsigned long long* __restrict__ hxch, int* __restrict__ flags,
                float* __restrict__ c_state)
{
  __shared__ unsigned short h_sh[64 * 264];   // 33792 B
  __shared__ unsigned short x_sh[64 * 264];   // 33792 B (L0: G0 staging)
  __shared__ float bias_sh[1024];             // 4096 B
  __shared__ short wih_lds[16 * 4 * 512];     // 65536 B   (total ~137 KB <= 160)
  __shared__ int len_sh[64];

  // XCD-aware role decode (launch = 128 blocks; R13's PROVEN mapping):
  // the 4 hb partners of a group share bid%8 == same XCD (FETCH -38%).
  const int bid  = blockIdx.x;                // 0..127
  const int xcd  = bid & 7;
  const int j    = bid >> 3;                  // 0..15 slot on this XCD
  const int g    = (j >> 2) * 8 + xcd;        // logical group 0..31
  if (g >= 30) return;
  const int L  = g / 10;
  const int S  = g % 10;
  const int hb = j & 3;

  if (L == 0)
    rec_stage<0>(S, hb, Whhp_all,          nullptr, G0, nullptr,
                 hxch, flags, lens, c_state, h_sh, x_sh, bias_sh, wih_lds, len_sh);
  else if (L == 1)
    rec_stage<1>(S, hb, Whhp_all + 262144, Wih1p, G0, biasc + G4,
                 hxch, flags, lens, c_state, h_sh, x_sh, bias_sh, wih_lds, len_sh);
  else
    rec_stage<2>(S, hb, Whhp_all + 524288, Wih2p, G0, biasc + 2 * G4,
                 hxch, flags, lens, c_state, h_sh, x_sh, bias_sh, wih_lds, len_sh);
}

// ---------------------------------------------------------------------------
// Epilogue (verified R1-R11). E aliases c_state.
// ---------------------------------------------------------------------------
__global__ void k_norm(const float* __restrict__ E, float* __restrict__ E1,
                       float* __restrict__ En) {
  int row  = blockIdx.x * 4 + (threadIdx.x >> 6);
  int lane = threadIdx.x & 63;
  const float* e = E + (size_t)row * H_DIM;
  float v[4]; float ss = 0.f;
#pragma unroll
  for (int j = 0; j < 4; ++j) { v[j] = e[lane + 64 * j]; ss += v[j] * v[j]; }
#pragma unroll
  for (int m = 32; m >= 1; m >>= 1) ss += __shfl_xor(ss, m, 64);
  float nrm  = sqrtf(ss);
  float inv1 = 1.f / fmaxf(nrm, 1e-12f);
  float inv2 = 1.f / fmaxf(nrm * inv1, 1e-8f);
#pragma unroll
  for (int j = 0; j < 4; ++j) {
    float e1 = v[j] * inv1;
    E1[(size_t)row * H_DIM + lane + 64 * j] = e1;
    En[(size_t)row * H_DIM + lane + 64 * j] = e1 * inv2;
  }
}

__global__ void k_cent(const float* __restrict__ E1, float* __restrict__ C,
                       float* __restrict__ CnT) {
  int n = blockIdx.x;
  int lane = threadIdx.x;  // 64
  float v[4]; float ss = 0.f;
#pragma unroll
  for (int j = 0; j < 4; ++j) {
    int col = lane + 64 * j;
    float s = 0.f;
    for (int m = 0; m < M_UTT; ++m) s += E1[((size_t)n * M_UTT + m) * H_DIM + col];
    v[j] = s / (float)M_UTT;
    ss += v[j] * v[j];
  }
#pragma unroll
  for (int m = 32; m >= 1; m >>= 1) ss += __shfl_xor(ss, m, 64);
  float inv = 1.f / fmaxf(sqrtf(ss), 1e-8f);
#pragma unroll
  for (int j = 0; j < 4; ++j) {
    int col = lane + 64 * j;
    C[(size_t)n * H_DIM + col]  = v[j];
    CnT[(size_t)col * N_SPK + n] = v[j] * inv;
  }
}

__global__ void k_cm(const float* __restrict__ E1, const float* __restrict__ C,
                     float* __restrict__ Cmn) {
  int b    = blockIdx.x * 4 + (threadIdx.x >> 6);
  int lane = threadIdx.x & 63;
  int spk  = b / M_UTT;
  float v[4]; float ss = 0.f;
#pragma unroll
  for (int j = 0; j < 4; ++j) {
    int col = lane + 64 * j;
    v[j] = ((float)M_UTT * C[(size_t)spk * H_DIM + col] + E1[(size_t)b * H_DIM + col])
           / (float)(M_UTT - 1);
    ss += v[j] * v[j];
  }
#pragma unroll
  for (int m = 32; m >= 1; m >>= 1) ss += __shfl_xor(ss, m, 64);
  float inv = 1.f / fmaxf(sqrtf(ss), 1e-8f);
#pragma unroll
  for (int j = 0; j < 4; ++j)
    Cmn[(size_t)b * H_DIM + lane + 64 * j] = v[j] * inv;
}

__global__ void k_sim(const float* __restrict__ En, const float* __restrict__ CnT,
                      const float* __restrict__ Cmn, const float* __restrict__ w_sim,
                      const float* __restrict__ b_sim, float* __restrict__ S) {
  int b = blockIdx.x;
  int n = threadIdx.x;  // 64
  int diag = b / M_UTT;
  float w = w_sim[0], bb = b_sim[0];
  float s = 0.f;
  for (int k = 0; k < H_DIM; ++k) {
    float en = En[(size_t)b * H_DIM + k];
    float c  = (n == diag) ? Cmn[(size_t)b * H_DIM + k] : CnT[(size_t)k * N_SPK + n];
    s += en * c;
  }
  S[(size_t)b * N_SPK + n] = s * w + bb;
}

// ---------------------------------------------------------------------------
// Workspace layout (bytes). Total ~219 MB (proven available). R13 map.
// ---------------------------------------------------------------------------
#define O_WHH   0ull            // 3 x 524288 = 1572864
#define O_WIH0  1572864ull      // 131072
#define O_WIH1  1703936ull      // 524288
#define O_WIH2  2228224ull      // 524288
#define O_BIAS  2752512ull      // 12288
#define O_CST   2764800ull      // 655360 (fp32 c of layer2 = E)
#define O_E1    3420160ull      // 655360
#define O_EN    4075520ull      // 655360
#define O_C     4730880ull      // 65536
#define O_CNT   4796416ull      // 65536
#define O_CMN   4861952ull      // 655360
#define O_FLG   5517312ull      // 30720 (120 flags x 256 B)
#define O_HXCH  5548032ull      // 3932160 (4par x 3l x 10S x 4hb x 8KB)
#define O_G0    9480192ull      // 209715200 -> end 219195392

extern "C" void kernel_launch(void* const* d_in, const int* in_sizes, int n_in,
                              void* d_out, int out_size, void* d_ws, size_t ws_size,
                              hipStream_t stream) {
  const float* seq   = (const float*)d_in[0];
  const int*   lens  = (const int*)d_in[1];
  const float* w_sim = (const float*)d_in[2];
  const float* b_sim = (const float*)d_in[3];
  const float* Wih[3] = {(const float*)d_in[4],  (const float*)d_in[8],  (const float*)d_in[12]};
  const float* Whh[3] = {(const float*)d_in[5],  (const float*)d_in[9],  (const float*)d_in[13]};
  const float* bih[3] = {(const float*)d_in[6],  (const float*)d_in[10], (const float*)d_in[14]};
  const float* bhh[3] = {(const float*)d_in[7],  (const float*)d_in[11], (const float*)d_in[15]};

  char* ws = (char*)d_ws;
  short* Whhp_all = (short*)(ws + O_WHH);
  short* Wihp[3] = {(short*)(ws + O_WIH0), (short*)(ws + O_WIH1), (short*)(ws + O_WIH2)};
  float* biasc = (float*)(ws + O_BIAS);
  float* c_state = (float*)(ws + O_CST);
  float* E1  = (float*)(ws + O_E1);
  float* En  = (float*)(ws + O_EN);
  float* C   = (float*)(ws + O_C);
  float* CnT = (float*)(ws + O_CNT);
  float* Cmn = (float*)(ws + O_CMN);
  int* flags = (int*)(ws + O_FLG);
  unsigned long long* hxch = (unsigned long long*)(ws + O_HXCH);
  unsigned short* G0 = (unsigned short*)(ws + O_G0);
  float* S = (float*)d_out;

  // ---- merged packs: 6 pack launches + 3 bias launches -> 2 launches ----
  pack_all_kernel<<<672, 256, 0, stream>>>(Wih[0], Whh[0], Whh[1], Whh[2],
                                           Wih[1], Wih[2],
                                           Wihp[0], Whhp_all, Wihp[1], Wihp[2]);
  bias_all_kernel<<<12, 256, 0, stream>>>(bih[0], bhh[0], bih[1], bhh[1],
                                          bih[2], bhh[2], biasc);

  // ---- layer-0 gate GEMM (full T, bias folded) ----
  gate_gemm0<<<1600, 256, 0, stream>>>(seq, Wihp[0], biasc, G0);

  // ---- fused 3-layer pipeline (R17 verbatim, 128 blocks) ----
  (void)hipMemsetAsync(ws + O_FLG, 0, 30720, stream);
  fused_lstm<<<128, 256, 0, stream>>>(Whhp_all, Wihp[1], Wihp[2], biasc, G0, lens,
                                      hxch, flags, c_state);

  // ---- similarity epilogue (E = c_state) ----
  k_norm<<<160, 256, 0, stream>>>(c_state, E1, En);
  k_cent<<<N_SPK, 64, 0, stream>>>(E1, C, CnT);
  k_cm<<<160, 256, 0, stream>>>(E1, C, Cmn);
  k_sim<<<B_TOT, 64, 0, stream>>>(En, CnT, Cmn, w_sim, b_sim, S);
}